// Round 21
// baseline (62.273 us; speedup 1.0000x reference)
//
#include <hip/hip_runtime.h>
#include <hip/hip_cooperative_groups.h>
#include <stdint.h>

namespace cg = cooperative_groups;

typedef uint16_t u16;
typedef __attribute__((ext_vector_type(8))) short    bf16x8;  // 8 bf16 (4 VGPRs)
typedef __attribute__((ext_vector_type(8))) uint16_t u16x8;
typedef __attribute__((ext_vector_type(4))) float    f32x4;

#define B_    2
#define N_    100000
#define K_    26
#define CIN_  32
#define COUT_ 32
#define MID2  50000                                  // node-range split

#define XT_ROWS  (N_ + 2)                            // + fill row (N_), + spare
#define XT_BYTES ((size_t)B_ * XT_ROWS * CIN_ * 2)

// ---- prep kernel geometry (xt [B][N+2][32] bf16 64B rows, Wb [32][832] bf16) ----
#define TCHUNK      64
#define TBLK_PER_B  ((N_ + TCHUNK - 1) / TCHUNK)     // 1563
#define TBLKS       (B_ * TBLK_PER_B)                // 3126
#define WBLKS       13                               // 13 * 2048 = 26624 W elems
#define PREP_GRID   (TBLKS + 1 + WBLKS)

// ---- conv kernel geometry ----
// R20: occupancy cell (12 waves/CU, deep ring). 768-thr blocks (12 waves),
// grid 256 = 1 block/CU, waves_per_eu(3,3) -> 170-reg budget (ring survives,
// per R18/R19 evidence at 256-budget). 4 tiles/wave, shared-k interleave,
// exec-masked 2-pass gathers, coop grid.sync. Completes the 8/12/16-waves
// matrix: null here => TA-throughput roofline established.
#define CONV_GRID   256
#define WPB12       1536                             // waves per batch
#define TILES_PB    (N_ / 16)                        // 6250
#define TAIL        (TILES_PB - 4 * WPB12)           // 106
#define WPITCH      840                              // W LDS row pitch

__device__ __forceinline__ u16 f2bf(float f) {
    union { float f; uint32_t u; } v; v.f = f;
    return (u16)((v.u + 0x7FFFu + ((v.u >> 16) & 1u)) >> 16);  // RNE
}

__global__ __launch_bounds__(256) void prep_kernel(
    const float* __restrict__ inp, const float* __restrict__ W,
    const float* __restrict__ fill, u16* __restrict__ xt, u16* __restrict__ Wb)
{
    int tid = threadIdx.x;
    int blk = blockIdx.x;
    if (blk >= TBLKS) {
        int job = blk - TBLKS;
        if (job == 0) {
            if (tid < 64) {                            // fill row at N_
                int b = tid >> 5, c = tid & 31;
                xt[((size_t)b * XT_ROWS + N_) * CIN_ + c] = f2bf(fill[c]);
            }
        } else {
            int base = (job - 1) * 2048 + tid * 8;    // exact: 13*2048 = 26624
            const float4* src = (const float4*)(W + base);
            float4 x = src[0], y = src[1];
            u16x8 o;
            o[0] = f2bf(x.x); o[1] = f2bf(x.y); o[2] = f2bf(x.z); o[3] = f2bf(x.w);
            o[4] = f2bf(y.x); o[5] = f2bf(y.y); o[6] = f2bf(y.z); o[7] = f2bf(y.w);
            *(u16x8*)(Wb + base) = o;
        }
        return;
    }
    __shared__ u16 tile[64][40];
    int b  = blk / TBLK_PER_B;
    int n0 = (blk % TBLK_PER_B) * TCHUNK;
    const float* inb = inp + (size_t)b * CIN_ * N_;
    #pragma unroll
    for (int it = 0; it < 8; ++it) {
        int idx = it * 256 + tid;
        int c = idx >> 6, n = idx & 63;
        if (n0 + n < N_) tile[n][c] = f2bf(inb[(size_t)c * N_ + n0 + n]);
    }
    __syncthreads();
    int n = tid >> 2, seg = tid & 3;
    if (n0 + n < N_) {
        u16x8 v = *(const u16x8*)&tile[n][seg * 8];
        *(u16x8*)(xt + ((size_t)b * XT_ROWS + n0 + n) * CIN_ + seg * 8) = v;
    }
}

#define MFMA16(a, b, c) __builtin_amdgcn_mfma_f32_16x16x32_bf16((a), (b), (c), 0, 0, 0)
#define GLD(ia)   (*(const bf16x8*)(xg + ((size_t)(ia) << 5)))

// Exec-masked pass gather: idx always in [0, N_]; pass 0 takes ix<MID2,
// pass 1 takes ix>=MID2 (incl. fill row N_). Out-of-range lanes: fragment
// zeroed, NO address issued (divergent if -> exec-masked global_load).
#define MGLD(dst, ixexpr) do {                                   \
    int ix_ = (ixexpr);                                          \
    bool inr_ = ((ix_ < MID2) != pb);                            \
    (dst) = (bf16x8)(short)0;                                    \
    if (inr_) (dst) = GLD((uint32_t)ix_);                        \
} while (0)

// Gather + MFMA GEMM: node-range 2-pass (3.2MB slice/XCD, coop grid.sync),
// shared-k 4-tile interleave, gather ring depth 4, W register double-buffer,
// exec-masked gathers. W + ALL idx in LDS -> in-loop VMEM = gathers only.
template<bool COOP>
__global__ __launch_bounds__(768)
__attribute__((amdgpu_waves_per_eu(3, 3)))
void conv_kernel(
    const u16* __restrict__ xt, const u16* __restrict__ Wb,
    const int* __restrict__ nbr, const float* __restrict__ bias,
    float* __restrict__ out)
{
    __shared__ u16 Wl[COUT_ * WPITCH];                // 53,760 B
    __shared__ int idxl[12][4][416];                  // 79,872 B; total 133,632 B
    int tid = threadIdx.x, bid = blockIdx.x;
    int xcd = bid & 7, slot = bid >> 3;               // slot 0..31
    int b   = xcd >> 2;                               // batch -> XCD half
    int wv  = tid >> 6, lane = tid & 63;
    int l15 = lane & 15, g = lane >> 4;
    int w   = (slot * 4 + (xcd & 3)) * 12 + wv;       // wave id in batch [0,1536)

    for (int i = tid; i < 3328; i += 768) {           // stage W
        int row = i / 104, c8 = i - row * 104;
        *(u16x8*)&Wl[row * WPITCH + c8 * 8] = *(const u16x8*)(Wb + row * 832 + c8 * 8);
    }

    const int* nbb  = nbr + (size_t)b * N_ * K_;
    float*     outb = out + (size_t)b * COUT_ * N_;
    const u16* xg   = xt + (size_t)b * XT_ROWS * CIN_ + (g << 3);
    const u16* wl   = &Wl[l15 * WPITCH + (g << 3)];

    #pragma unroll
    for (int j = 0; j < 4; ++j) {                     // idx tiles 0..3 -> LDS
        const int* src = nbb + (size_t)(w + j * WPB12) * 416;
        int* dst = idxl[wv][j];
        #pragma unroll
        for (int r = 0; r < 7; ++r) {
            int i = r * 64 + lane;
            if (i < 416) dst[i] = src[i];
        }
    }
    __syncthreads();

    f32x4 a00 = 0.0f, a01 = 0.0f, a10 = 0.0f, a11 = 0.0f;
    f32x4 a20 = 0.0f, a21 = 0.0f, a30 = 0.0f, a31 = 0.0f;
    const int* ql0 = &idxl[wv][0][l15 * 26];
    const int* ql1 = &idxl[wv][1][l15 * 26];
    const int* ql2 = &idxl[wv][2][l15 * 26];
    const int* ql3 = &idxl[wv][3][l15 * 26];

    #pragma unroll 1
    for (int p = 0; p < 2; ++p) {                     // node-range pass
        const int pb = p;                             // mask polarity

        bf16x8 f0[4], f1[4], f2[4], f3[4];            // 4-tile ring, depth 4
        bf16x8 wa[2], wb2[2];                         // W register double-buffer
        #pragma unroll
        for (int k = 0; k < 4; ++k) {
            MGLD(f0[k], ql0[k]);
            MGLD(f1[k], ql1[k]);
            MGLD(f2[k], ql2[k]);
            MGLD(f3[k], ql3[k]);
        }
        wa[0]  = *(const bf16x8*)(wl);
        wb2[0] = *(const bf16x8*)(wl + 16 * WPITCH);
        __builtin_amdgcn_sched_barrier(0);

        #pragma unroll
        for (int k = 0; k < 26; ++k) {
            const int cur = k & 1, nxt = cur ^ 1;
            const int s = k & 3;                      // static under full unroll
            if (k < 25) {                             // W(k+1) -> regs (hides lgkm)
                wa[nxt]  = *(const bf16x8*)(wl + (k + 1) * 32);
                wb2[nxt] = *(const bf16x8*)(wl + 16 * WPITCH + (k + 1) * 32);
            }
            a00 = MFMA16(wa[cur], f0[s], a00);  a01 = MFMA16(wb2[cur], f0[s], a01);
            a10 = MFMA16(wa[cur], f1[s], a10);  a11 = MFMA16(wb2[cur], f1[s], a11);
            a20 = MFMA16(wa[cur], f2[s], a20);  a21 = MFMA16(wb2[cur], f2[s], a21);
            a30 = MFMA16(wa[cur], f3[s], a30);  a31 = MFMA16(wb2[cur], f3[s], a31);
            if (k < 22) {                             // refill slot s with k+4
                MGLD(f0[s], ql0[k + 4]);
                MGLD(f1[s], ql1[k + 4]);
                MGLD(f2[s], ql2[k + 4]);
                MGLD(f3[s], ql3[k + 4]);
            }
            __builtin_amdgcn_sched_barrier(0);        // pin pipeline shape
        }

        if (p == 0) {
            if constexpr (COOP) cg::this_grid().sync();   // HARD phase alignment
            else __syncthreads();
        }
    }

    // ---- epilogue: D col = l15 -> node, D row = g*4+r -> o ----
    float bs0[4], bs1[4];
    #pragma unroll
    for (int r = 0; r < 4; ++r) {
        bs0[r] = bias[g * 4 + r];
        bs1[r] = bias[g * 4 + r + 16];
    }
    {
        int node = w * 16 + l15;
        #pragma unroll
        for (int r = 0; r < 4; ++r) {
            outb[(size_t)(g * 4 + r) * N_ + node]      = a00[r] + bs0[r];
            outb[(size_t)(g * 4 + r + 16) * N_ + node] = a01[r] + bs1[r];
        }
    }
    {
        int node = (w + WPB12) * 16 + l15;
        #pragma unroll
        for (int r = 0; r < 4; ++r) {
            outb[(size_t)(g * 4 + r) * N_ + node]      = a10[r] + bs0[r];
            outb[(size_t)(g * 4 + r + 16) * N_ + node] = a11[r] + bs1[r];
        }
    }
    {
        int node = (w + 2 * WPB12) * 16 + l15;
        #pragma unroll
        for (int r = 0; r < 4; ++r) {
            outb[(size_t)(g * 4 + r) * N_ + node]      = a20[r] + bs0[r];
            outb[(size_t)(g * 4 + r + 16) * N_ + node] = a21[r] + bs1[r];
        }
    }
    {
        int node = (w + 3 * WPB12) * 16 + l15;
        #pragma unroll
        for (int r = 0; r < 4; ++r) {
            outb[(size_t)(g * 4 + r) * N_ + node]      = a30[r] + bs0[r];
            outb[(size_t)(g * 4 + r + 16) * N_ + node] = a31[r] + bs1[r];
        }
    }

    // ---- tail: 106 tiles per batch, unsplit, after both passes ----
    if (w < TAIL) {
        int t4 = 4 * WPB12 + w;
        const int* qp4 = nbb + ((size_t)t4 * 16 + l15) * K_;
        int q[26];
        #pragma unroll
        for (int k = 0; k < 26; ++k) q[k] = qp4[k];
        f32x4 c0 = 0.0f, c1 = 0.0f;
        bf16x8 f[4];
        bf16x8 wa[2], wb2[2];
        #pragma unroll
        for (int k = 0; k < 4; ++k) f[k] = GLD((uint32_t)q[k]);
        wa[0]  = *(const bf16x8*)(wl);
        wb2[0] = *(const bf16x8*)(wl + 16 * WPITCH);
        __builtin_amdgcn_sched_barrier(0);
        #pragma unroll
        for (int k = 0; k < 26; ++k) {
            const int cur = k & 1, nxt = cur ^ 1;
            const int s = k & 3;
            if (k < 25) {
                wa[nxt]  = *(const bf16x8*)(wl + (k + 1) * 32);
                wb2[nxt] = *(const bf16x8*)(wl + 16 * WPITCH + (k + 1) * 32);
            }
            c0 = MFMA16(wa[cur], f[s], c0);
            c1 = MFMA16(wb2[cur], f[s], c1);
            if (k < 22) f[s] = GLD((uint32_t)q[k + 4]);
            __builtin_amdgcn_sched_barrier(0);
        }
        int node = t4 * 16 + l15;
        #pragma unroll
        for (int r = 0; r < 4; ++r) {
            outb[(size_t)(g * 4 + r) * N_ + node]      = c0[r] + bs0[r];
            outb[(size_t)(g * 4 + r + 16) * N_ + node] = c1[r] + bs1[r];
        }
    }
}

extern "C" void kernel_launch(void* const* d_in, const int* in_sizes, int n_in,
                              void* d_out, int out_size, void* d_ws, size_t ws_size,
                              hipStream_t stream) {
    (void)in_sizes; (void)n_in; (void)out_size; (void)ws_size;
    const float* inp  = (const float*)d_in[0];
    const int*   nbr  = (const int*)d_in[1];
    const float* W    = (const float*)d_in[2];
    const float* bias = (const float*)d_in[3];
    const float* fill = (const float*)d_in[4];
    float* out = (float*)d_out;

    u16* xt = (u16*)d_ws;                              // [B][N+2][32] bf16
    u16* Wb = (u16*)((char*)d_ws + XT_BYTES);          // [32][832] bf16

    prep_kernel<<<PREP_GRID, 256, 0, stream>>>(inp, W, fill, xt, Wb);

    const u16* xta = xt; const u16* Wba = Wb;
    const int* nbra = nbr; const float* biasa = bias; float* outa = out;
    void* args[] = { (void*)&xta, (void*)&Wba, (void*)&nbra, (void*)&biasa, (void*)&outa };

    int maxb = 0;
    hipError_t oe = hipOccupancyMaxActiveBlocksPerMultiprocessor(
        &maxb, reinterpret_cast<const void*>(&conv_kernel<true>), 768, 0);
    hipError_t e = hipErrorUnknown;
    if (oe == hipSuccess && maxb * 256 >= CONV_GRID) {
        e = hipLaunchCooperativeKernel(
            reinterpret_cast<const void*>(&conv_kernel<true>),
            dim3(CONV_GRID), dim3(768), args, 0u, stream);
    }
    if (e != hipSuccess) {
        conv_kernel<false><<<CONV_GRID, 768, 0, stream>>>(xta, Wba, nbra, biasa, outa);
    }
}

// Round 22
// 60.672 us; speedup vs baseline: 1.0264x; 1.0264x over previous
//
#include <hip/hip_runtime.h>
#include <hip/hip_cooperative_groups.h>
#include <stdint.h>

namespace cg = cooperative_groups;

typedef uint16_t u16;
typedef __attribute__((ext_vector_type(8))) short    bf16x8;  // 8 bf16 (4 VGPRs)
typedef __attribute__((ext_vector_type(8))) uint16_t u16x8;
typedef __attribute__((ext_vector_type(4))) float    f32x4;

#define B_    2
#define N_    100000
#define K_    26
#define CIN_  32
#define COUT_ 32
#define MID2  50000                                  // node-range split

#define XT_ROWS  (N_ + 2)                            // + fill row (N_), + spare
#define XT_BYTES ((size_t)B_ * XT_ROWS * CIN_ * 2)

// ---- prep kernel geometry (xt [B][N+2][32] bf16 64B rows, Wb [32][832] bf16) ----
#define TCHUNK      64
#define TBLK_PER_B  ((N_ + TCHUNK - 1) / TCHUNK)     // 1563
#define TBLKS       (B_ * TBLK_PER_B)                // 3126
#define WBLKS       13                               // 13 * 2048 = 26624 W elems
#define PREP_GRID   (TBLKS + 1 + WBLKS)

// ---- conv kernel geometry ----
// FINAL (R19 config, measured optimum of the 8/12/16-waves matrix):
// 512-thr blocks (8 waves), grid 256 = 1 block/CU, waves_per_eu(2,2) =
// 256-reg budget (ring materializes, VGPR 92). Node-range 2-pass with coop
// grid.sync -> 3.2MB gather slice L2-resident per XCD (FETCH 40MB, minimal).
// Exec-masked gathers: each (node,k) address processed by TA exactly once
// across both passes. Shared-k 6-tile interleave amortizes W ds_reads 12x.
// W + ALL idx in LDS -> in-loop VMEM = gathers only (counted vmcnt).
// Remaining cost is the structural TA/issue floor for random 64B gathers.
#define CONV_GRID   256
#define WPB8        1024                             // waves per batch
#define TILES_PB    (N_ / 16)                        // 6250
#define TAIL        (TILES_PB - 6 * WPB8)            // 106
#define WPITCH      840                              // W LDS row pitch

__device__ __forceinline__ u16 f2bf(float f) {
    union { float f; uint32_t u; } v; v.f = f;
    return (u16)((v.u + 0x7FFFu + ((v.u >> 16) & 1u)) >> 16);  // RNE
}

__global__ __launch_bounds__(256) void prep_kernel(
    const float* __restrict__ inp, const float* __restrict__ W,
    const float* __restrict__ fill, u16* __restrict__ xt, u16* __restrict__ Wb)
{
    int tid = threadIdx.x;
    int blk = blockIdx.x;
    if (blk >= TBLKS) {
        int job = blk - TBLKS;
        if (job == 0) {
            if (tid < 64) {                            // fill row at N_
                int b = tid >> 5, c = tid & 31;
                xt[((size_t)b * XT_ROWS + N_) * CIN_ + c] = f2bf(fill[c]);
            }
        } else {
            int base = (job - 1) * 2048 + tid * 8;    // exact: 13*2048 = 26624
            const float4* src = (const float4*)(W + base);
            float4 x = src[0], y = src[1];
            u16x8 o;
            o[0] = f2bf(x.x); o[1] = f2bf(x.y); o[2] = f2bf(x.z); o[3] = f2bf(x.w);
            o[4] = f2bf(y.x); o[5] = f2bf(y.y); o[6] = f2bf(y.z); o[7] = f2bf(y.w);
            *(u16x8*)(Wb + base) = o;
        }
        return;
    }
    __shared__ u16 tile[64][40];
    int b  = blk / TBLK_PER_B;
    int n0 = (blk % TBLK_PER_B) * TCHUNK;
    const float* inb = inp + (size_t)b * CIN_ * N_;
    #pragma unroll
    for (int it = 0; it < 8; ++it) {
        int idx = it * 256 + tid;
        int c = idx >> 6, n = idx & 63;
        if (n0 + n < N_) tile[n][c] = f2bf(inb[(size_t)c * N_ + n0 + n]);
    }
    __syncthreads();
    int n = tid >> 2, seg = tid & 3;
    if (n0 + n < N_) {
        u16x8 v = *(const u16x8*)&tile[n][seg * 8];
        *(u16x8*)(xt + ((size_t)b * XT_ROWS + n0 + n) * CIN_ + seg * 8) = v;
    }
}

#define MFMA16(a, b, c) __builtin_amdgcn_mfma_f32_16x16x32_bf16((a), (b), (c), 0, 0, 0)
#define GLD(ia)   (*(const bf16x8*)(xg + ((size_t)(ia) << 5)))

// Exec-masked pass gather: idx always in [0, N_]; pass 0 takes ix<MID2,
// pass 1 takes ix>=MID2 (incl. fill row N_). Out-of-range lanes: fragment
// zeroed, NO address issued (divergent if -> exec-masked global_load).
#define MGLD(dst, ixexpr) do {                                   \
    int ix_ = (ixexpr);                                          \
    bool inr_ = ((ix_ < MID2) != pb);                            \
    (dst) = (bf16x8)(short)0;                                    \
    if (inr_) (dst) = GLD((uint32_t)ix_);                        \
} while (0)

// Gather + MFMA GEMM: node-range 2-pass (3.2MB slice/XCD, coop grid.sync),
// shared-k 6-tile interleave, gather ring depth 4, W register double-buffer,
// exec-masked gathers. W + ALL idx in LDS -> in-loop VMEM = gathers only.
template<bool COOP>
__global__ __launch_bounds__(512)
__attribute__((amdgpu_waves_per_eu(2, 2)))
void conv_kernel(
    const u16* __restrict__ xt, const u16* __restrict__ Wb,
    const int* __restrict__ nbr, const float* __restrict__ bias,
    float* __restrict__ out)
{
    __shared__ u16 Wl[COUT_ * WPITCH];                // 53,760 B
    __shared__ int idxl[8][6][416];                   // 79,872 B; total 133,632 B
    int tid = threadIdx.x, bid = blockIdx.x;
    int xcd = bid & 7, slot = bid >> 3;               // slot 0..31
    int b   = xcd >> 2;                               // batch -> XCD half
    int wv  = tid >> 6, lane = tid & 63;
    int l15 = lane & 15, g = lane >> 4;
    int w   = (slot * 4 + (xcd & 3)) * 8 + wv;        // wave id in batch [0,1024)

    for (int i = tid; i < 3328; i += 512) {           // stage W
        int row = i / 104, c8 = i - row * 104;
        *(u16x8*)&Wl[row * WPITCH + c8 * 8] = *(const u16x8*)(Wb + row * 832 + c8 * 8);
    }

    const int* nbb  = nbr + (size_t)b * N_ * K_;
    float*     outb = out + (size_t)b * COUT_ * N_;
    const u16* xg   = xt + (size_t)b * XT_ROWS * CIN_ + (g << 3);
    const u16* wl   = &Wl[l15 * WPITCH + (g << 3)];

    #pragma unroll
    for (int j = 0; j < 6; ++j) {                     // idx tiles 0..5 -> LDS
        const int* src = nbb + (size_t)(w + j * WPB8) * 416;
        int* dst = idxl[wv][j];
        #pragma unroll
        for (int r = 0; r < 7; ++r) {
            int i = r * 64 + lane;
            if (i < 416) dst[i] = src[i];
        }
    }
    __syncthreads();

    f32x4 a00 = 0.0f, a01 = 0.0f, a10 = 0.0f, a11 = 0.0f, a20 = 0.0f, a21 = 0.0f;
    f32x4 a30 = 0.0f, a31 = 0.0f, a40 = 0.0f, a41 = 0.0f, a50 = 0.0f, a51 = 0.0f;
    const int* ql0 = &idxl[wv][0][l15 * 26];
    const int* ql1 = &idxl[wv][1][l15 * 26];
    const int* ql2 = &idxl[wv][2][l15 * 26];
    const int* ql3 = &idxl[wv][3][l15 * 26];
    const int* ql4 = &idxl[wv][4][l15 * 26];
    const int* ql5 = &idxl[wv][5][l15 * 26];

    #pragma unroll 1
    for (int p = 0; p < 2; ++p) {                     // node-range pass
        const int pb = p;                             // mask polarity

        bf16x8 f0[4], f1[4], f2[4], f3[4], f4[4], f5[4];  // 6-tile ring, depth 4
        bf16x8 wa[2], wb2[2];                         // W register double-buffer
        #pragma unroll
        for (int k = 0; k < 4; ++k) {
            MGLD(f0[k], ql0[k]);
            MGLD(f1[k], ql1[k]);
            MGLD(f2[k], ql2[k]);
            MGLD(f3[k], ql3[k]);
            MGLD(f4[k], ql4[k]);
            MGLD(f5[k], ql5[k]);
        }
        wa[0]  = *(const bf16x8*)(wl);
        wb2[0] = *(const bf16x8*)(wl + 16 * WPITCH);
        __builtin_amdgcn_sched_barrier(0);

        #pragma unroll
        for (int k = 0; k < 26; ++k) {
            const int cur = k & 1, nxt = cur ^ 1;
            const int s = k & 3;                      // static under full unroll
            if (k < 25) {                             // W(k+1) -> regs (hides lgkm)
                wa[nxt]  = *(const bf16x8*)(wl + (k + 1) * 32);
                wb2[nxt] = *(const bf16x8*)(wl + 16 * WPITCH + (k + 1) * 32);
            }
            a00 = MFMA16(wa[cur], f0[s], a00);  a01 = MFMA16(wb2[cur], f0[s], a01);
            a10 = MFMA16(wa[cur], f1[s], a10);  a11 = MFMA16(wb2[cur], f1[s], a11);
            a20 = MFMA16(wa[cur], f2[s], a20);  a21 = MFMA16(wb2[cur], f2[s], a21);
            a30 = MFMA16(wa[cur], f3[s], a30);  a31 = MFMA16(wb2[cur], f3[s], a31);
            a40 = MFMA16(wa[cur], f4[s], a40);  a41 = MFMA16(wb2[cur], f4[s], a41);
            a50 = MFMA16(wa[cur], f5[s], a50);  a51 = MFMA16(wb2[cur], f5[s], a51);
            if (k < 22) {                             // refill slot s with k+4
                MGLD(f0[s], ql0[k + 4]);
                MGLD(f1[s], ql1[k + 4]);
                MGLD(f2[s], ql2[k + 4]);
                MGLD(f3[s], ql3[k + 4]);
                MGLD(f4[s], ql4[k + 4]);
                MGLD(f5[s], ql5[k + 4]);
            }
            __builtin_amdgcn_sched_barrier(0);        // pin pipeline shape
        }

        if (p == 0) {
            if constexpr (COOP) cg::this_grid().sync();   // HARD phase alignment
            else __syncthreads();
        }
    }

    // ---- epilogue: D col = l15 -> node, D row = g*4+r -> o ----
    float bs0[4], bs1[4];
    #pragma unroll
    for (int r = 0; r < 4; ++r) {
        bs0[r] = bias[g * 4 + r];
        bs1[r] = bias[g * 4 + r + 16];
    }
    {
        int node = w * 16 + l15;
        #pragma unroll
        for (int r = 0; r < 4; ++r) {
            outb[(size_t)(g * 4 + r) * N_ + node]      = a00[r] + bs0[r];
            outb[(size_t)(g * 4 + r + 16) * N_ + node] = a01[r] + bs1[r];
        }
    }
    {
        int node = (w + WPB8) * 16 + l15;
        #pragma unroll
        for (int r = 0; r < 4; ++r) {
            outb[(size_t)(g * 4 + r) * N_ + node]      = a10[r] + bs0[r];
            outb[(size_t)(g * 4 + r + 16) * N_ + node] = a11[r] + bs1[r];
        }
    }
    {
        int node = (w + 2 * WPB8) * 16 + l15;
        #pragma unroll
        for (int r = 0; r < 4; ++r) {
            outb[(size_t)(g * 4 + r) * N_ + node]      = a20[r] + bs0[r];
            outb[(size_t)(g * 4 + r + 16) * N_ + node] = a21[r] + bs1[r];
        }
    }
    {
        int node = (w + 3 * WPB8) * 16 + l15;
        #pragma unroll
        for (int r = 0; r < 4; ++r) {
            outb[(size_t)(g * 4 + r) * N_ + node]      = a30[r] + bs0[r];
            outb[(size_t)(g * 4 + r + 16) * N_ + node] = a31[r] + bs1[r];
        }
    }
    {
        int node = (w + 4 * WPB8) * 16 + l15;
        #pragma unroll
        for (int r = 0; r < 4; ++r) {
            outb[(size_t)(g * 4 + r) * N_ + node]      = a40[r] + bs0[r];
            outb[(size_t)(g * 4 + r + 16) * N_ + node] = a41[r] + bs1[r];
        }
    }
    {
        int node = (w + 5 * WPB8) * 16 + l15;
        #pragma unroll
        for (int r = 0; r < 4; ++r) {
            outb[(size_t)(g * 4 + r) * N_ + node]      = a50[r] + bs0[r];
            outb[(size_t)(g * 4 + r + 16) * N_ + node] = a51[r] + bs1[r];
        }
    }

    // ---- tail: 106 tiles per batch, unsplit, after both passes ----
    if (w < TAIL) {
        int t6 = 6 * WPB8 + w;
        const int* qp6 = nbb + ((size_t)t6 * 16 + l15) * K_;
        int q[26];
        #pragma unroll
        for (int k = 0; k < 26; ++k) q[k] = qp6[k];
        f32x4 c0 = 0.0f, c1 = 0.0f;
        bf16x8 f[4];
        bf16x8 wa[2], wb2[2];
        #pragma unroll
        for (int k = 0; k < 4; ++k) f[k] = GLD((uint32_t)q[k]);
        wa[0]  = *(const bf16x8*)(wl);
        wb2[0] = *(const bf16x8*)(wl + 16 * WPITCH);
        __builtin_amdgcn_sched_barrier(0);
        #pragma unroll
        for (int k = 0; k < 26; ++k) {
            const int cur = k & 1, nxt = cur ^ 1;
            const int s = k & 3;
            if (k < 25) {
                wa[nxt]  = *(const bf16x8*)(wl + (k + 1) * 32);
                wb2[nxt] = *(const bf16x8*)(wl + 16 * WPITCH + (k + 1) * 32);
            }
            c0 = MFMA16(wa[cur], f[s], c0);
            c1 = MFMA16(wb2[cur], f[s], c1);
            if (k < 22) f[s] = GLD((uint32_t)q[k + 4]);
            __builtin_amdgcn_sched_barrier(0);
        }
        int node = t6 * 16 + l15;
        #pragma unroll
        for (int r = 0; r < 4; ++r) {
            outb[(size_t)(g * 4 + r) * N_ + node]      = c0[r] + bs0[r];
            outb[(size_t)(g * 4 + r + 16) * N_ + node] = c1[r] + bs1[r];
        }
    }
}

extern "C" void kernel_launch(void* const* d_in, const int* in_sizes, int n_in,
                              void* d_out, int out_size, void* d_ws, size_t ws_size,
                              hipStream_t stream) {
    (void)in_sizes; (void)n_in; (void)out_size; (void)ws_size;
    const float* inp  = (const float*)d_in[0];
    const int*   nbr  = (const int*)d_in[1];
    const float* W    = (const float*)d_in[2];
    const float* bias = (const float*)d_in[3];
    const float* fill = (const float*)d_in[4];
    float* out = (float*)d_out;

    u16* xt = (u16*)d_ws;                              // [B][N+2][32] bf16
    u16* Wb = (u16*)((char*)d_ws + XT_BYTES);          // [32][832] bf16

    prep_kernel<<<PREP_GRID, 256, 0, stream>>>(inp, W, fill, xt, Wb);

    const u16* xta = xt; const u16* Wba = Wb;
    const int* nbra = nbr; const float* biasa = bias; float* outa = out;
    void* args[] = { (void*)&xta, (void*)&Wba, (void*)&nbra, (void*)&biasa, (void*)&outa };

    int maxb = 0;
    hipError_t oe = hipOccupancyMaxActiveBlocksPerMultiprocessor(
        &maxb, reinterpret_cast<const void*>(&conv_kernel<true>), 512, 0);
    hipError_t e = hipErrorUnknown;
    if (oe == hipSuccess && maxb * 256 >= CONV_GRID) {
        e = hipLaunchCooperativeKernel(
            reinterpret_cast<const void*>(&conv_kernel<true>),
            dim3(CONV_GRID), dim3(512), args, 0u, stream);
    }
    if (e != hipSuccess) {
        conv_kernel<false><<<CONV_GRID, 512, 0, stream>>>(xta, Wba, nbra, biasa, outa);
    }
}